// Round 10
// baseline (440.575 us; speedup 1.0000x reference)
//
#include <hip/hip_runtime.h>
#include <hip/hip_bf16.h>
#include <cstdint>
#include <cstddef>

#define NN 20000
#define KK 32
#define HH 128
#define FFD 512
#define LN_EPS 1e-5f
#define NGRP 5000   // NN/4 node-groups
#define PGRID 256   // persistent blocks (1 per CU)

typedef __attribute__((ext_vector_type(8))) short bf16x8;
typedef __attribute__((ext_vector_type(4))) float f32x4;

__device__ __forceinline__ short f2b(float f){
  __hip_bfloat16 h = __float2bfloat16(f);
  return __builtin_bit_cast(short, h);
}
__device__ __forceinline__ float b2f(short s){
  union { unsigned int u; float f; } v; v.u = ((unsigned int)(unsigned short)s) << 16; return v.f;
}
__device__ __forceinline__ unsigned int pk2(float a, float b){
  return (unsigned int)(unsigned short)f2b(a) | ((unsigned int)(unsigned short)f2b(b) << 16);
}
// tanh-form GELU via hw exp2 + rcp
__device__ __forceinline__ float gelu_fast(float x){
  float u = x * __builtin_fmaf(0.10294278f, x*x, 2.3022082f);
  float e = __builtin_amdgcn_exp2f(u);
  float r = __builtin_amdgcn_rcpf(1.0f + e);
  return __builtin_fmaf(-x, r, x);
}
__device__ __forceinline__ f32x4 MFMA(bf16x8 a, bf16x8 b, f32x4 c){
  return __builtin_amdgcn_mfma_f32_16x16x32_bf16(a, b, c, 0, 0, 0);
}

// ---------------- weight packing (unchanged layout) ----------------
__global__ __launch_bounds__(256) void enc_pack(
    const float* __restrict__ W1, const float* __restrict__ W2, const float* __restrict__ W3,
    const float* __restrict__ W11, const float* __restrict__ W12, const float* __restrict__ W13,
    const float* __restrict__ Win, const float* __restrict__ Wout,
    short* __restrict__ pk)
{
  const int stride = gridDim.x * blockDim.x;
  for (int idx = blockIdx.x*blockDim.x + threadIdx.x; idx < 294912; idx += stride){
    const float* src = W2; int srow = 0, k, n, NT, NCOLS, base;
    if (idx < 163840){
      int slot = idx >> 14, e = idx & 16383;
      k = e >> 7; n = e & 127; NT = 8; NCOLS = 128; base = slot << 14;
      switch (slot){
        case 0: src = W1;  srow = 0;   break;
        case 1: src = W1;  srow = 256; break;
        case 2: src = W1;  srow = 128; break;
        case 3: src = W2;  srow = 0;   break;
        case 4: src = W3;  srow = 0;   break;
        case 5: src = W11; srow = 0;   break;
        case 6: src = W11; srow = 256; break;
        case 7: src = W11; srow = 128; break;
        case 8: src = W12; srow = 0;   break;
        default: src = W13; srow = 0;  break;
      }
    } else if (idx < 229376){
      int e = idx - 163840; k = e >> 9; n = e & 511; NT = 32; NCOLS = 512; src = Win; base = 163840;
    } else {
      int e = idx - 229376; k = e >> 7; n = e & 127; NT = 8; NCOLS = 128; src = Wout; base = 229376;
    }
    float v = src[(srow + k)*NCOLS + n];
    int out = base + (((k>>5)*NT + (n>>4))*64 + ((k>>3)&3)*16 + (n&15))*8 + (k&7);
    pk[out] = f2b(v);
  }
}

// ---------------- node projections: U = X@Wa + b, Z = X@Wc ----------------
__global__ __launch_bounds__(256, 2) void enc_proj(
    const float* __restrict__ X, const short* __restrict__ pkU, const short* __restrict__ pkZ,
    const float* __restrict__ biasU, short* __restrict__ U, short* __restrict__ Z)
{
  const int lane = threadIdx.x & 63, w = threadIdx.x >> 6;
  const int kgrp = lane >> 4, ccol = lane & 15;
  const int row0 = blockIdx.x*64 + w*16;
  const int arow = row0 + (lane & 15);
  f32x4 accU[8], accZ[8];
  #pragma unroll
  for (int nf=0;nf<8;nf++){ accU[nf] = (f32x4){0,0,0,0}; accZ[nf] = (f32x4){0,0,0,0}; }
  #pragma unroll
  for (int kt=0;kt<4;kt++){
    bf16x8 af = {0,0,0,0,0,0,0,0};
    if (arow < NN){
      const float4* p = (const float4*)(X + (size_t)arow*HH + kt*32 + kgrp*8);
      float4 v0 = p[0], v1 = p[1];
      af[0]=f2b(v0.x); af[1]=f2b(v0.y); af[2]=f2b(v0.z); af[3]=f2b(v0.w);
      af[4]=f2b(v1.x); af[5]=f2b(v1.y); af[6]=f2b(v1.z); af[7]=f2b(v1.w);
    }
    #pragma unroll
    for (int nf=0;nf<8;nf++){
      bf16x8 bu = *(const bf16x8*)(pkU + (((kt<<3)+nf)*64 + lane)*8);
      accU[nf] = MFMA(af, bu, accU[nf]);
      bf16x8 bz = *(const bf16x8*)(pkZ + (((kt<<3)+nf)*64 + lane)*8);
      accZ[nf] = MFMA(af, bz, accZ[nf]);
    }
  }
  #pragma unroll
  for (int nf=0;nf<8;nf++){
    #pragma unroll
    for (int r=0;r<4;r++){
      int grow = row0 + kgrp*4 + r;
      if (grow < NN){
        int col = nf*16 + ccol;
        U[(size_t)grow*HH + col] = f2b(accU[nf][r] + biasU[col]);
        Z[(size_t)grow*HH + col] = f2b(accZ[nf][r]);
      }
    }
  }
}

// ---------- persistent fused 3-layer edge MLP, all weights LDS-resident ----------
// 256 blocks x 512 threads, 1 block/CU (LDS ~139KB). Grid-stride over 5000 groups
// of 4 nodes (128 edge rows; wave w owns rows [w*16,w*16+16)). Weights staged to
// LDS once per CU. Inner loop: PASS1 zero barriers (all wave-local), PASS0 one
// (node-pair combine, parity-buffered sPart). Global reads software-pipelined:
// hE tile + Eidx/Z prefetched one iteration ahead; PASS1 residual issued before
// layer 2 and consumed after layer 3 (2 waves/SIMD -> latency must be hidden in
// registers; 1 block/CU gives 256-VGPR headroom, no spill).
#define LSTR 136
template<int PASS>
__global__ __launch_bounds__(512, 2) void enc_mlp3(
    const float* __restrict__ hE,
    const short* __restrict__ Ub, const short* __restrict__ Zb,
    const int*  __restrict__ Eidx,
    const float* __restrict__ maskAtt,
    const float* __restrict__ hV,
    const float* __restrict__ lnG, const float* __restrict__ lnB,
    const short* __restrict__ pkL1,
    const short* __restrict__ pkL2, const float* __restrict__ bias2,
    const short* __restrict__ pkL3, const float* __restrict__ bias3,
    float* __restrict__ outP)
{
  __shared__ __align__(16) short sW1[16384];      // 32KB
  __shared__ __align__(16) short sW2[16384];      // 32KB
  __shared__ __align__(16) short sW3[16384];      // 32KB
  __shared__ __align__(16) short sBuf[128*LSTR];  // 34816B
  __shared__ float sB23[256];
  __shared__ float sPart[2][8][128];              // parity-buffered (PASS0)

  const int t = threadIdx.x;
  const int lane = t & 63, w = t >> 6;          // w in 0..7
  const int kgrp = lane >> 4, ccol = lane & 15;
  const int rw = w*16;                          // wave's first block-local row
  const int zrow = rw + (lane >> 2);            // Z-gather row (4 lanes/row)
  const int seg0 = lane & 3;

  if (t < 256) sB23[t] = (t < 128) ? bias2[t] : bias3[t-128];
  // ---- stage all three weight matrices once ----
  #pragma unroll
  for (int it=0; it<4; it++){
    int idx = it*512 + t;
    *(int4*)(sW1 + idx*8) = *(const int4*)(pkL1 + idx*8);
    *(int4*)(sW2 + idx*8) = *(const int4*)(pkL2 + idx*8);
    *(int4*)(sW3 + idx*8) = *(const int4*)(pkL3 + idx*8);
  }
  __syncthreads();

  const short* sRow = sBuf + (rw + ccol)*LSTR;
  const int stg_r = (lane>>5);      // staging row offset (0/1)
  const int stg_c = lane & 31;      // staging float4 col

  // ---- prologue prefetch for first group ----
  int grp = blockIdx.x;
  float4 pf[8];
  int4 z0g, z1g, z2g, z3g;
  if (grp < NGRP){
    const float4* src = (const float4*)(hE + ((size_t)grp*128 + rw)*HH);
    #pragma unroll
    for (int it=0; it<8; it++) pf[it] = src[(it*2 + stg_r)*32 + stg_c];
    int jj = Eidx[grp*128 + zrow];
    const int4* zsrc = (const int4*)(Zb + (size_t)jj*HH);
    z0g = zsrc[seg0]; z1g = zsrc[seg0+4]; z2g = zsrc[seg0+8]; z3g = zsrc[seg0+12];
  }
  int pb = 0;

  for (; grp < NGRP; grp += PGRID){
    const int nxt = grp + PGRID;
    const size_t ebase = (size_t)grp*128;        // first edge row of group
    const int node = grp*4 + (w >> 1);

    // ---- stage hE tile from prefetched regs ----
    #pragma unroll
    for (int it=0; it<8; it++){
      uint2 p; p.x = pk2(pf[it].x, pf[it].y); p.y = pk2(pf[it].z, pf[it].w);
      *(uint2*)(sBuf + (rw + it*2 + stg_r)*LSTR + stg_c*4) = p;
    }
    // issue next-iter hE prefetch (in flight across whole iteration)
    if (nxt < NGRP){
      const float4* srcn = (const float4*)(hE + ((size_t)nxt*128 + rw)*HH);
      #pragma unroll
      for (int it=0; it<8; it++) pf[it] = srcn[(it*2 + stg_r)*32 + stg_c];
    }
    // next-iter Eidx (dependent Z loads issued mid-iteration)
    int jn = 0;
    if (nxt < NGRP) jn = Eidx[nxt*128 + zrow];
    // this-iter U rows (L2-hot scalar loads, consumed in epilogue 1)
    float ureg[8];
    #pragma unroll
    for (int nf=0; nf<8; nf++) ureg[nf] = b2f(Ub[(size_t)node*HH + nf*16 + ccol]);
    float m[4];
    if (PASS == 0){
      const float4 mv = *(const float4*)(maskAtt + ebase + rw + kgrp*4);
      m[0]=mv.x; m[1]=mv.y; m[2]=mv.z; m[3]=mv.w;
    }

    f32x4 acc[8];
    // ---- layer 1 ----
    #pragma unroll
    for (int nf=0;nf<8;nf++) acc[nf] = (f32x4){0,0,0,0};
    #pragma unroll
    for (int kt=0;kt<4;kt++){
      bf16x8 af = *(const bf16x8*)(sRow + kt*32 + kgrp*8);
      #pragma unroll
      for (int nf=0;nf<8;nf++){
        bf16x8 b = *(const bf16x8*)(sW1 + (((kt<<3)+nf)*64 + lane)*8);
        acc[nf] = MFMA(af, b, acc[nf]);
      }
    }
    // Z write (prefetched last iteration); rows wave-private, LDS ops in-order
    *(int4*)(sBuf + zrow*LSTR + (seg0     )*8) = z0g;
    *(int4*)(sBuf + zrow*LSTR + (seg0 + 4 )*8) = z1g;
    *(int4*)(sBuf + zrow*LSTR + (seg0 + 8 )*8) = z2g;
    *(int4*)(sBuf + zrow*LSTR + (seg0 + 12)*8) = z3g;
    // issue next-iter Z gather (consumed next iteration)
    if (nxt < NGRP){
      const int4* zsn = (const int4*)(Zb + (size_t)jn*HH);
      z0g = zsn[seg0]; z1g = zsn[seg0+4]; z2g = zsn[seg0+8]; z3g = zsn[seg0+12];
    }
    // epilogue 1: +U +Z, gelu -> msg1 (same LDS slots)
    #pragma unroll
    for (int nf=0;nf<8;nf++){
      #pragma unroll
      for (int r=0;r<4;r++){
        short* p = sBuf + (rw + kgrp*4 + r)*LSTR + nf*16 + ccol;
        float v = acc[nf][r] + ureg[nf] + b2f(*p);
        *p = f2b(gelu_fast(v));
      }
    }
    // PASS1: issue residual loads now (consumed after layer 3)
    float res[32];
    if (PASS == 1){
      #pragma unroll
      for (int nf=0;nf<8;nf++){
        #pragma unroll
        for (int r=0;r<4;r++)
          res[nf*4+r] = hE[(ebase + rw + kgrp*4 + r)*HH + nf*16 + ccol];
      }
    }
    // ---- layer 2 ----
    #pragma unroll
    for (int nf=0;nf<8;nf++) acc[nf] = (f32x4){0,0,0,0};
    #pragma unroll
    for (int kt=0;kt<4;kt++){
      bf16x8 af = *(const bf16x8*)(sRow + kt*32 + kgrp*8);
      #pragma unroll
      for (int nf=0;nf<8;nf++){
        bf16x8 b = *(const bf16x8*)(sW2 + (((kt<<3)+nf)*64 + lane)*8);
        acc[nf] = MFMA(af, b, acc[nf]);
      }
    }
    #pragma unroll
    for (int nf=0;nf<8;nf++){
      float b2v = sB23[nf*16 + ccol];
      #pragma unroll
      for (int r=0;r<4;r++){
        short* p = sBuf + (rw + kgrp*4 + r)*LSTR + nf*16 + ccol;
        *p = f2b(gelu_fast(acc[nf][r] + b2v));
      }
    }
    // ---- layer 3 ----
    #pragma unroll
    for (int nf=0;nf<8;nf++) acc[nf] = (f32x4){0,0,0,0};
    #pragma unroll
    for (int kt=0;kt<4;kt++){
      bf16x8 af = *(const bf16x8*)(sRow + kt*32 + kgrp*8);
      #pragma unroll
      for (int nf=0;nf<8;nf++){
        bf16x8 b = *(const bf16x8*)(sW3 + (((kt<<3)+nf)*64 + lane)*8);
        acc[nf] = MFMA(af, b, acc[nf]);
      }
    }

    if (PASS == 0){
      #pragma unroll
      for (int nf=0;nf<8;nf++){
        float b3v = sB23[128 + nf*16 + ccol];
        float s = 0.f;
        #pragma unroll
        for (int r=0;r<4;r++) s = __builtin_fmaf(acc[nf][r] + b3v, m[r], s);
        s += __shfl_xor(s, 16);
        s += __shfl_xor(s, 32);
        if (kgrp == 0) sPart[pb][w][nf*16 + ccol] = s;
      }
      __syncthreads();
      if ((w & 1) == 0){
        float c0 = sPart[pb][w][lane]    + sPart[pb][w+1][lane];
        float c1 = sPart[pb][w][64+lane] + sPart[pb][w+1][64+lane];
        float x0 = hV[(size_t)node*HH + lane]      + c0*(1.0f/30.0f);
        float x1 = hV[(size_t)node*HH + 64 + lane] + c1*(1.0f/30.0f);
        float sm = x0 + x1, sq = x0*x0 + x1*x1;
        #pragma unroll
        for (int off=1; off<64; off<<=1){
          sm += __shfl_xor(sm, off);
          sq += __shfl_xor(sq, off);
        }
        float mean = sm*(1.f/128.f);
        float var  = sq*(1.f/128.f) - mean*mean;
        float inv  = rsqrtf(var + LN_EPS);
        outP[(size_t)node*HH + lane]      = (x0-mean)*inv*lnG[lane]    + lnB[lane];
        outP[(size_t)node*HH + 64 + lane] = (x1-mean)*inv*lnG[64+lane] + lnB[64+lane];
      }
      pb ^= 1;
    } else {
      float rs[4] = {0,0,0,0}, rq[4] = {0,0,0,0};
      #pragma unroll
      for (int nf=0;nf<8;nf++){
        float b3v = sB23[128 + nf*16 + ccol];
        #pragma unroll
        for (int r=0;r<4;r++){
          float x = acc[nf][r] + b3v + res[nf*4+r];
          acc[nf][r] = x;
          rs[r] += x; rq[r] += x*x;
        }
      }
      #pragma unroll
      for (int off=1; off<16; off<<=1){
        #pragma unroll
        for (int r=0;r<4;r++){
          rs[r] += __shfl_xor(rs[r], off);
          rq[r] += __shfl_xor(rq[r], off);
        }
      }
      #pragma unroll
      for (int r=0;r<4;r++){
        float mean = rs[r]*(1.f/128.f);
        float var  = rq[r]*(1.f/128.f) - mean*mean;
        float inv  = rsqrtf(var + LN_EPS);
        #pragma unroll
        for (int nf=0;nf<8;nf++){
          outP[(ebase + rw + kgrp*4 + r)*HH + nf*16 + ccol] =
              (acc[nf][r]-mean)*inv*lnG[nf*16 + ccol] + lnB[nf*16 + ccol];
        }
      }
    }
  }
}

// ---------------- fused FFN 128->512->128 + LN2 + mask_V ----------------
__global__ __launch_bounds__(256, 2) void enc_ffn(
    const float* __restrict__ X,
    const short* __restrict__ pkWin, const float* __restrict__ bin,
    const short* __restrict__ pkWout, const float* __restrict__ bout,
    const float* __restrict__ g2, const float* __restrict__ b2ln,
    const float* __restrict__ maskV,
    float* __restrict__ out)
{
  __shared__ short sT[64*512];
  const int t = threadIdx.x, lane = t & 63, w = t >> 6;
  const int kgrp = lane >> 4, ccol = lane & 15;
  const int row0 = blockIdx.x*64;
  const int arow = row0 + w*16 + (lane & 15);
  f32x4 acc[32];
  #pragma unroll
  for (int nf=0;nf<32;nf++) acc[nf] = (f32x4){0,0,0,0};
  #pragma unroll
  for (int kt=0;kt<4;kt++){
    bf16x8 af = {0,0,0,0,0,0,0,0};
    if (arow < NN){
      const float4* p = (const float4*)(X + (size_t)arow*HH + kt*32 + kgrp*8);
      float4 v0 = p[0], v1 = p[1];
      af[0]=f2b(v0.x); af[1]=f2b(v0.y); af[2]=f2b(v0.z); af[3]=f2b(v0.w);
      af[4]=f2b(v1.x); af[5]=f2b(v1.y); af[6]=f2b(v1.z); af[7]=f2b(v1.w);
    }
    #pragma unroll
    for (int nf=0;nf<32;nf++){
      bf16x8 b = *(const bf16x8*)(pkWin + ((size_t)((kt<<5)+nf)*64 + lane)*8);
      acc[nf] = MFMA(af, b, acc[nf]);
    }
  }
  #pragma unroll
  for (int nf=0;nf<32;nf++){
    #pragma unroll
    for (int r=0;r<4;r++){
      int rl = w*16 + kgrp*4 + r, col = nf*16 + ccol;
      sT[rl*512 + (col ^ ((rl&7)<<3))] = f2b(gelu_fast(acc[nf][r] + bin[col]));
    }
  }
  f32x4 a2[8];
  #pragma unroll
  for (int nf=0;nf<8;nf++) a2[nf] = (f32x4){0,0,0,0};
  const int rl_a = w*16 + (lane & 15);
  #pragma unroll
  for (int kt=0;kt<16;kt++){
    int base = kt*32 + kgrp*8;
    bf16x8 af = *(const bf16x8*)(sT + rl_a*512 + (base ^ ((rl_a&7)<<3)));
    #pragma unroll
    for (int nf=0;nf<8;nf++){
      bf16x8 b = *(const bf16x8*)(pkWout + (((kt<<3)+nf)*64 + lane)*8);
      a2[nf] = MFMA(af, b, a2[nf]);
    }
  }
  float rsum[4] = {0,0,0,0}, rsq[4] = {0,0,0,0};
  #pragma unroll
  for (int nf=0;nf<8;nf++){
    #pragma unroll
    for (int r=0;r<4;r++){
      int grow = row0 + w*16 + kgrp*4 + r, col = nf*16 + ccol;
      float prev = (grow < NN) ? X[(size_t)grow*HH + col] : 0.f;
      float x = a2[nf][r] + bout[col] + prev;
      a2[nf][r] = x;
      rsum[r] += x; rsq[r] += x*x;
    }
  }
  #pragma unroll
  for (int off=1; off<16; off<<=1){
    #pragma unroll
    for (int r=0;r<4;r++){
      rsum[r] += __shfl_xor(rsum[r], off);
      rsq[r]  += __shfl_xor(rsq[r], off);
    }
  }
  #pragma unroll
  for (int r=0;r<4;r++){
    int grow = row0 + w*16 + kgrp*4 + r;
    float mean = rsum[r]*(1.f/128.f);
    float var  = rsq[r]*(1.f/128.f) - mean*mean;
    float inv  = rsqrtf(var + LN_EPS);
    float mv   = (grow < NN) ? maskV[grow] : 0.f;
    #pragma unroll
    for (int nf=0;nf<8;nf++){
      int col = nf*16 + ccol;
      if (grow < NN)
        out[(size_t)grow*HH + col] = mv * ((a2[nf][r]-mean)*inv*g2[col] + b2ln[col]);
    }
  }
}

// ---------------- host ----------------
extern "C" void kernel_launch(void* const* d_in, const int* in_sizes, int n_in,
                              void* d_out, int out_size, void* d_ws, size_t ws_size,
                              hipStream_t stream)
{
  const float* h_V   = (const float*)d_in[0];
  const float* h_E   = (const float*)d_in[1];
  const float* maskV = (const float*)d_in[2];
  const float* maskA = (const float*)d_in[3];
  const float* W1w  = (const float*)d_in[4];  const float* W1b  = (const float*)d_in[5];
  const float* W2w  = (const float*)d_in[6];  const float* W2b  = (const float*)d_in[7];
  const float* W3w  = (const float*)d_in[8];  const float* W3b  = (const float*)d_in[9];
  const float* W11w = (const float*)d_in[10]; const float* W11b = (const float*)d_in[11];
  const float* W12w = (const float*)d_in[12]; const float* W12b = (const float*)d_in[13];
  const float* W13w = (const float*)d_in[14]; const float* W13b = (const float*)d_in[15];
  const float* Winw = (const float*)d_in[16]; const float* Winb = (const float*)d_in[17];
  const float* Woutw= (const float*)d_in[18]; const float* Woutb= (const float*)d_in[19];
  const float* ln1g = (const float*)d_in[20]; const float* ln1b = (const float*)d_in[21];
  const float* ln2g = (const float*)d_in[22]; const float* ln2b = (const float*)d_in[23];
  const float* ln3g = (const float*)d_in[24]; const float* ln3b = (const float*)d_in[25];
  const int*   Eidx = (const int*)d_in[26];

  float* outV = (float*)d_out;
  float* outE = outV + (size_t)NN*HH;

  char* ws = (char*)d_ws;
  short* pk = (short*)ws;
  const short* pkW1a  = pk + 0*16384;
  const short* pkW1c  = pk + 1*16384;
  const short* pkW1bb = pk + 2*16384;
  const short* pkW2   = pk + 3*16384;
  const short* pkW3   = pk + 4*16384;
  const short* pkW11a = pk + 5*16384;
  const short* pkW11c = pk + 6*16384;
  const short* pkW11bb= pk + 7*16384;
  const short* pkW12  = pk + 8*16384;
  const short* pkW13  = pk + 9*16384;
  const short* pkWin  = pk + 163840;
  const short* pkWout = pk + 229376;

  short* U1 = (short*)(ws + 1048576);
  short* Z1 = (short*)(ws + 6291456);
  short* U2 = (short*)(ws + 11534336);
  short* Z2 = (short*)(ws + 16777216);
  float* hVmid = (float*)(ws + 22020096);

  enc_pack<<<288, 256, 0, stream>>>(W1w, W2w, W3w, W11w, W12w, W13w, Winw, Woutw, pk);
  enc_proj<<<313, 256, 0, stream>>>(h_V, pkW1a, pkW1c, W1b, U1, Z1);
  enc_mlp3<0><<<PGRID, 512, 0, stream>>>(h_E, U1, Z1, Eidx, maskA, h_V,
                                         ln1g, ln1b, pkW1bb, pkW2, W2b, pkW3, W3b, hVmid);
  enc_ffn<<<313, 256, 0, stream>>>(hVmid, pkWin, Winb, pkWout, Woutb,
                                   ln2g, ln2b, maskV, outV);
  enc_proj<<<313, 256, 0, stream>>>(outV, pkW11a, pkW11c, W11b, U2, Z2);
  enc_mlp3<1><<<PGRID, 512, 0, stream>>>(h_E, U2, Z2, Eidx, nullptr, nullptr,
                                         ln3g, ln3b, pkW11bb, pkW12, W12b, pkW13, W13b, outE);
}

// Round 11
// 417.202 us; speedup vs baseline: 1.0560x; 1.0560x over previous
//
#include <hip/hip_runtime.h>
#include <hip/hip_bf16.h>
#include <cstdint>
#include <cstddef>

#define NN 20000
#define KK 32
#define HH 128
#define FFD 512
#define LN_EPS 1e-5f

typedef __attribute__((ext_vector_type(8))) short bf16x8;
typedef __attribute__((ext_vector_type(4))) float f32x4;

__device__ __forceinline__ short f2b(float f){
  __hip_bfloat16 h = __float2bfloat16(f);
  return __builtin_bit_cast(short, h);
}
__device__ __forceinline__ float b2f(short s){
  union { unsigned int u; float f; } v; v.u = ((unsigned int)(unsigned short)s) << 16; return v.f;
}
__device__ __forceinline__ unsigned int pk2(float a, float b){
  return (unsigned int)(unsigned short)f2b(a) | ((unsigned int)(unsigned short)f2b(b) << 16);
}
// tanh-form GELU via hw exp2 + rcp
__device__ __forceinline__ float gelu_fast(float x){
  float u = x * __builtin_fmaf(0.10294278f, x*x, 2.3022082f);
  float e = __builtin_amdgcn_exp2f(u);
  float r = __builtin_amdgcn_rcpf(1.0f + e);
  return __builtin_fmaf(-x, r, x);
}
__device__ __forceinline__ f32x4 MFMA(bf16x8 a, bf16x8 b, f32x4 c){
  return __builtin_amdgcn_mfma_f32_16x16x32_bf16(a, b, c, 0, 0, 0);
}

// ---------------- weight packing ----------------
__global__ __launch_bounds__(256) void enc_pack(
    const float* __restrict__ W1, const float* __restrict__ W2, const float* __restrict__ W3,
    const float* __restrict__ W11, const float* __restrict__ W12, const float* __restrict__ W13,
    const float* __restrict__ Win, const float* __restrict__ Wout,
    short* __restrict__ pk)
{
  const int stride = gridDim.x * blockDim.x;
  for (int idx = blockIdx.x*blockDim.x + threadIdx.x; idx < 294912; idx += stride){
    const float* src = W2; int srow = 0, k, n, NT, NCOLS, base;
    if (idx < 163840){
      int slot = idx >> 14, e = idx & 16383;
      k = e >> 7; n = e & 127; NT = 8; NCOLS = 128; base = slot << 14;
      switch (slot){
        case 0: src = W1;  srow = 0;   break;
        case 1: src = W1;  srow = 256; break;
        case 2: src = W1;  srow = 128; break;
        case 3: src = W2;  srow = 0;   break;
        case 4: src = W3;  srow = 0;   break;
        case 5: src = W11; srow = 0;   break;
        case 6: src = W11; srow = 256; break;
        case 7: src = W11; srow = 128; break;
        case 8: src = W12; srow = 0;   break;
        default: src = W13; srow = 0;  break;
      }
    } else if (idx < 229376){
      int e = idx - 163840; k = e >> 9; n = e & 511; NT = 32; NCOLS = 512; src = Win; base = 163840;
    } else {
      int e = idx - 229376; k = e >> 7; n = e & 127; NT = 8; NCOLS = 128; src = Wout; base = 229376;
    }
    float v = src[(srow + k)*NCOLS + n];
    int out = base + (((k>>5)*NT + (n>>4))*64 + ((k>>3)&3)*16 + (n&15))*8 + (k&7);
    pk[out] = f2b(v);
  }
}

// ---------------- node projections: U = X@Wa + b, Z = X@Wc ----------------
__global__ __launch_bounds__(256, 2) void enc_proj(
    const float* __restrict__ X, const short* __restrict__ pkU, const short* __restrict__ pkZ,
    const float* __restrict__ biasU, short* __restrict__ U, short* __restrict__ Z)
{
  const int lane = threadIdx.x & 63, w = threadIdx.x >> 6;
  const int kgrp = lane >> 4, ccol = lane & 15;
  const int row0 = blockIdx.x*64 + w*16;
  const int arow = row0 + (lane & 15);
  f32x4 accU[8], accZ[8];
  #pragma unroll
  for (int nf=0;nf<8;nf++){ accU[nf] = (f32x4){0,0,0,0}; accZ[nf] = (f32x4){0,0,0,0}; }
  #pragma unroll
  for (int kt=0;kt<4;kt++){
    bf16x8 af = {0,0,0,0,0,0,0,0};
    if (arow < NN){
      const float4* p = (const float4*)(X + (size_t)arow*HH + kt*32 + kgrp*8);
      float4 v0 = p[0], v1 = p[1];
      af[0]=f2b(v0.x); af[1]=f2b(v0.y); af[2]=f2b(v0.z); af[3]=f2b(v0.w);
      af[4]=f2b(v1.x); af[5]=f2b(v1.y); af[6]=f2b(v1.z); af[7]=f2b(v1.w);
    }
    #pragma unroll
    for (int nf=0;nf<8;nf++){
      bf16x8 bu = *(const bf16x8*)(pkU + (((kt<<3)+nf)*64 + lane)*8);
      accU[nf] = MFMA(af, bu, accU[nf]);
      bf16x8 bz = *(const bf16x8*)(pkZ + (((kt<<3)+nf)*64 + lane)*8);
      accZ[nf] = MFMA(af, bz, accZ[nf]);
    }
  }
  #pragma unroll
  for (int nf=0;nf<8;nf++){
    #pragma unroll
    for (int r=0;r<4;r++){
      int grow = row0 + kgrp*4 + r;
      if (grow < NN){
        int col = nf*16 + ccol;
        U[(size_t)grow*HH + col] = f2b(accU[nf][r] + biasU[col]);
        Z[(size_t)grow*HH + col] = f2b(accZ[nf][r]);
      }
    }
  }
}

// ---------------- fused 3-layer edge MLP (8 waves, 4 nodes/block) ----------------
// R9 chassis. EM=1: PASS0 additionally writes the bf16 image of h_E (hEs) from its
// staging registers; PASS1 stages from hEs (half the fetch bytes, no cvt VALU) and
// takes the residual from hEs (L2-hot). EM=0: exact R9 behavior (fp32 h_E).
#define LSTR 136
template<int PASS, int EM>
__global__ __launch_bounds__(512, 4) void enc_mlp3(
    const float* __restrict__ hE,
    const short* __restrict__ Ub, const short* __restrict__ Zb,
    const int*  __restrict__ Eidx,
    const float* __restrict__ maskAtt,
    const float* __restrict__ hV,
    const float* __restrict__ lnG, const float* __restrict__ lnB,
    const short* __restrict__ pkL1,
    const short* __restrict__ pkL2, const float* __restrict__ bias2,
    const short* __restrict__ pkL3, const float* __restrict__ bias3,
    float* __restrict__ outP,
    short* __restrict__ hEs)
{
  __shared__ __align__(16) short sBuf[128*LSTR];  // 34816 B activations
  __shared__ __align__(16) short sW[16384];       // 32768 B current-layer weights
  __shared__ float sB23[256];
  __shared__ float sPart[8][128];

  const int i0 = blockIdx.x*4;
  const int t = threadIdx.x;
  const int lane = t & 63, w = t >> 6;          // w in 0..7
  const int kgrp = lane >> 4, ccol = lane & 15;
  const int node = i0 + (w >> 1);
  const int rw = w*16;
  const size_t ebase = (size_t)i0*KK;           // first edge row of block

  if (t < 256) sB23[t] = (t < 128) ? bias2[t] : bias3[t-128];

  // ---- stage W1 into LDS ----
  #pragma unroll
  for (int it=0; it<4; it++){
    int idx = it*512 + t;
    *(int4*)(sW + idx*8) = *(const int4*)(pkL1 + idx*8);
  }

  // ---- stage h_E rows rw..rw+15 (wave-local) ----
  if constexpr (EM == 1 && PASS == 1){
    // bf16 source: pure int4 copy
    const short* srcS = hEs + (ebase + rw)*HH;
    #pragma unroll
    for (int it=0; it<4; it++){
      int r16 = it*4 + (lane>>4);
      int c16 = lane & 15;
      int4 v = *(const int4*)(srcS + (size_t)r16*HH + c16*8);
      *(int4*)(sBuf + (rw + r16)*LSTR + c16*8) = v;
    }
  } else {
    // fp32 source -> bf16 (PASS0 always; PASS1 when EM=0)
    const float4* src = (const float4*)(hE + (ebase + rw)*HH);
    #pragma unroll
    for (int it=0; it<8; it++){
      int r = it*2 + (lane>>5);
      int c4 = lane & 31;
      float4 v = src[r*32 + c4];
      uint2 p; p.x = pk2(v.x, v.y); p.y = pk2(v.z, v.w);
      *(uint2*)(sBuf + (rw + r)*LSTR + c4*4) = p;
      if constexpr (EM == 1 && PASS == 0)
        *(uint2*)(hEs + (ebase + rw + r)*HH + c4*4) = p;   // bf16 image for PASS1
    }
  }
  __syncthreads();   // W1 + sB23 visible

  const short* sRow = sBuf + (rw + ccol)*LSTR;
  f32x4 acc[8];

  // ---- layer 1 ----
  #pragma unroll
  for (int nf=0;nf<8;nf++) acc[nf] = (f32x4){0,0,0,0};
  #pragma unroll
  for (int kt=0;kt<4;kt++){
    bf16x8 af = *(const bf16x8*)(sRow + kt*32 + kgrp*8);
    #pragma unroll
    for (int nf=0;nf<8;nf++){
      bf16x8 b = *(const bf16x8*)(sW + (((kt<<3)+nf)*64 + lane)*8);
      acc[nf] = MFMA(af, b, acc[nf]);
    }
  }
  // Z gather (short liveness); rows wave-private
  {
    const int zrow = rw + (lane >> 2);
    const int seg0 = lane & 3;
    const int jj = Eidx[i0*KK + zrow];
    const int4* zsrc = (const int4*)(Zb + (size_t)jj*HH);
    int4 z0 = zsrc[seg0];
    int4 z1 = zsrc[seg0 + 4];
    int4 z2 = zsrc[seg0 + 8];
    int4 z3 = zsrc[seg0 + 12];
    *(int4*)(sBuf + zrow*LSTR + (seg0     )*8) = z0;
    *(int4*)(sBuf + zrow*LSTR + (seg0 + 4 )*8) = z1;
    *(int4*)(sBuf + zrow*LSTR + (seg0 + 8 )*8) = z2;
    *(int4*)(sBuf + zrow*LSTR + (seg0 + 12)*8) = z3;
  }
  __syncthreads();   // all waves done reading W1
  // stage W2 (overlaps epilogue-1)
  #pragma unroll
  for (int it=0; it<4; it++){
    int idx = it*512 + t;
    *(int4*)(sW + idx*8) = *(const int4*)(pkL2 + idx*8);
  }
  // epilogue 1: +U +Z, gelu -> msg1
  #pragma unroll
  for (int nf=0;nf<8;nf++){
    float uv = b2f(Ub[(size_t)node*HH + nf*16 + ccol]);
    #pragma unroll
    for (int r=0;r<4;r++){
      short* p = sBuf + (rw + kgrp*4 + r)*LSTR + nf*16 + ccol;
      float v = acc[nf][r] + uv + b2f(*p);
      *p = f2b(gelu_fast(v));
    }
  }
  __syncthreads();   // W2 visible

  // ---- layer 2 ----
  #pragma unroll
  for (int nf=0;nf<8;nf++) acc[nf] = (f32x4){0,0,0,0};
  #pragma unroll
  for (int kt=0;kt<4;kt++){
    bf16x8 af = *(const bf16x8*)(sRow + kt*32 + kgrp*8);
    #pragma unroll
    for (int nf=0;nf<8;nf++){
      bf16x8 b = *(const bf16x8*)(sW + (((kt<<3)+nf)*64 + lane)*8);
      acc[nf] = MFMA(af, b, acc[nf]);
    }
  }
  __syncthreads();   // all waves done reading W2
  // stage W3 (overlaps epilogue-2)
  #pragma unroll
  for (int it=0; it<4; it++){
    int idx = it*512 + t;
    *(int4*)(sW + idx*8) = *(const int4*)(pkL3 + idx*8);
  }
  #pragma unroll
  for (int nf=0;nf<8;nf++){
    float b2v = sB23[nf*16 + ccol];
    #pragma unroll
    for (int r=0;r<4;r++){
      short* p = sBuf + (rw + kgrp*4 + r)*LSTR + nf*16 + ccol;
      *p = f2b(gelu_fast(acc[nf][r] + b2v));
    }
  }
  __syncthreads();   // W3 visible

  // ---- layer 3 ----
  #pragma unroll
  for (int nf=0;nf<8;nf++) acc[nf] = (f32x4){0,0,0,0};
  #pragma unroll
  for (int kt=0;kt<4;kt++){
    bf16x8 af = *(const bf16x8*)(sRow + kt*32 + kgrp*8);
    #pragma unroll
    for (int nf=0;nf<8;nf++){
      bf16x8 b = *(const bf16x8*)(sW + (((kt<<3)+nf)*64 + lane)*8);
      acc[nf] = MFMA(af, b, acc[nf]);
    }
  }

  if (PASS == 0){
    float m[4];
    {
      const float4 mv = *(const float4*)(maskAtt + ebase + rw + kgrp*4);
      m[0]=mv.x; m[1]=mv.y; m[2]=mv.z; m[3]=mv.w;
    }
    #pragma unroll
    for (int nf=0;nf<8;nf++){
      float b3v = sB23[128 + nf*16 + ccol];
      float s = 0.f;
      #pragma unroll
      for (int r=0;r<4;r++) s = __builtin_fmaf(acc[nf][r] + b3v, m[r], s);
      s += __shfl_xor(s, 16);
      s += __shfl_xor(s, 32);
      if (kgrp == 0) sPart[w][nf*16 + ccol] = s;
    }
    __syncthreads();
    if ((w & 1) == 0){
      float c0 = sPart[w][lane]    + sPart[w+1][lane];
      float c1 = sPart[w][64+lane] + sPart[w+1][64+lane];
      float x0 = hV[(size_t)node*HH + lane]      + c0*(1.0f/30.0f);
      float x1 = hV[(size_t)node*HH + 64 + lane] + c1*(1.0f/30.0f);
      float sm = x0 + x1, sq = x0*x0 + x1*x1;
      #pragma unroll
      for (int off=1; off<64; off<<=1){
        sm += __shfl_xor(sm, off);
        sq += __shfl_xor(sq, off);
      }
      float mean = sm*(1.f/128.f);
      float var  = sq*(1.f/128.f) - mean*mean;
      float inv  = rsqrtf(var + LN_EPS);
      outP[(size_t)node*HH + lane]      = (x0-mean)*inv*lnG[lane]    + lnB[lane];
      outP[(size_t)node*HH + 64 + lane] = (x1-mean)*inv*lnG[64+lane] + lnB[64+lane];
    }
  } else {
    // +b3, +h_E residual, LN3 in-register per row
    float rs[4] = {0,0,0,0}, rq[4] = {0,0,0,0};
    #pragma unroll
    for (int nf=0;nf<8;nf++){
      float b3v = sB23[128 + nf*16 + ccol];
      #pragma unroll
      for (int r=0;r<4;r++){
        int row = rw + kgrp*4 + r, col = nf*16 + ccol;
        float hres;
        if constexpr (EM == 1) hres = b2f(hEs[(ebase + row)*HH + col]);
        else                   hres = hE[(ebase + row)*HH + col];
        float x = acc[nf][r] + b3v + hres;
        acc[nf][r] = x;
        rs[r] += x; rq[r] += x*x;
      }
    }
    #pragma unroll
    for (int off=1; off<16; off<<=1){
      #pragma unroll
      for (int r=0;r<4;r++){
        rs[r] += __shfl_xor(rs[r], off);
        rq[r] += __shfl_xor(rq[r], off);
      }
    }
    #pragma unroll
    for (int r=0;r<4;r++){
      float mean = rs[r]*(1.f/128.f);
      float var  = rq[r]*(1.f/128.f) - mean*mean;
      float inv  = rsqrtf(var + LN_EPS);
      #pragma unroll
      for (int nf=0;nf<8;nf++){
        int row = rw + kgrp*4 + r, col = nf*16 + ccol;
        __builtin_nontemporal_store((acc[nf][r]-mean)*inv*lnG[col] + lnB[col],
                                    &outP[(ebase + row)*HH + col]);
      }
    }
  }
}

// ---------------- fused FFN 128->512->128 + LN2 + mask_V ----------------
__global__ __launch_bounds__(256, 2) void enc_ffn(
    const float* __restrict__ X,
    const short* __restrict__ pkWin, const float* __restrict__ bin,
    const short* __restrict__ pkWout, const float* __restrict__ bout,
    const float* __restrict__ g2, const float* __restrict__ b2ln,
    const float* __restrict__ maskV,
    float* __restrict__ out)
{
  __shared__ short sT[64*512];
  const int t = threadIdx.x, lane = t & 63, w = t >> 6;
  const int kgrp = lane >> 4, ccol = lane & 15;
  const int row0 = blockIdx.x*64;
  const int arow = row0 + w*16 + (lane & 15);
  f32x4 acc[32];
  #pragma unroll
  for (int nf=0;nf<32;nf++) acc[nf] = (f32x4){0,0,0,0};
  #pragma unroll
  for (int kt=0;kt<4;kt++){
    bf16x8 af = {0,0,0,0,0,0,0,0};
    if (arow < NN){
      const float4* p = (const float4*)(X + (size_t)arow*HH + kt*32 + kgrp*8);
      float4 v0 = p[0], v1 = p[1];
      af[0]=f2b(v0.x); af[1]=f2b(v0.y); af[2]=f2b(v0.z); af[3]=f2b(v0.w);
      af[4]=f2b(v1.x); af[5]=f2b(v1.y); af[6]=f2b(v1.z); af[7]=f2b(v1.w);
    }
    #pragma unroll
    for (int nf=0;nf<32;nf++){
      bf16x8 b = *(const bf16x8*)(pkWin + ((size_t)((kt<<5)+nf)*64 + lane)*8);
      acc[nf] = MFMA(af, b, acc[nf]);
    }
  }
  #pragma unroll
  for (int nf=0;nf<32;nf++){
    #pragma unroll
    for (int r=0;r<4;r++){
      int rl = w*16 + kgrp*4 + r, col = nf*16 + ccol;
      sT[rl*512 + (col ^ ((rl&7)<<3))] = f2b(gelu_fast(acc[nf][r] + bin[col]));
    }
  }
  f32x4 a2[8];
  #pragma unroll
  for (int nf=0;nf<8;nf++) a2[nf] = (f32x4){0,0,0,0};
  const int rl_a = w*16 + (lane & 15);
  #pragma unroll
  for (int kt=0;kt<16;kt++){
    int base = kt*32 + kgrp*8;
    bf16x8 af = *(const bf16x8*)(sT + rl_a*512 + (base ^ ((rl_a&7)<<3)));
    #pragma unroll
    for (int nf=0;nf<8;nf++){
      bf16x8 b = *(const bf16x8*)(pkWout + (((kt<<3)+nf)*64 + lane)*8);
      a2[nf] = MFMA(af, b, a2[nf]);
    }
  }
  float rsum[4] = {0,0,0,0}, rsq[4] = {0,0,0,0};
  #pragma unroll
  for (int nf=0;nf<8;nf++){
    #pragma unroll
    for (int r=0;r<4;r++){
      int grow = row0 + w*16 + kgrp*4 + r, col = nf*16 + ccol;
      float prev = (grow < NN) ? X[(size_t)grow*HH + col] : 0.f;
      float x = a2[nf][r] + bout[col] + prev;
      a2[nf][r] = x;
      rsum[r] += x; rsq[r] += x*x;
    }
  }
  #pragma unroll
  for (int off=1; off<16; off<<=1){
    #pragma unroll
    for (int r=0;r<4;r++){
      rsum[r] += __shfl_xor(rsum[r], off);
      rsq[r]  += __shfl_xor(rsq[r], off);
    }
  }
  #pragma unroll
  for (int r=0;r<4;r++){
    int grow = row0 + w*16 + kgrp*4 + r;
    float mean = rsum[r]*(1.f/128.f);
    float var  = rsq[r]*(1.f/128.f) - mean*mean;
    float inv  = rsqrtf(var + LN_EPS);
    float mv   = (grow < NN) ? maskV[grow] : 0.f;
    #pragma unroll
    for (int nf=0;nf<8;nf++){
      int col = nf*16 + ccol;
      if (grow < NN)
        out[(size_t)grow*HH + col] = mv * ((a2[nf][r]-mean)*inv*g2[col] + b2ln[col]);
    }
  }
}

// ---------------- host ----------------
extern "C" void kernel_launch(void* const* d_in, const int* in_sizes, int n_in,
                              void* d_out, int out_size, void* d_ws, size_t ws_size,
                              hipStream_t stream)
{
  const float* h_V   = (const float*)d_in[0];
  const float* h_E   = (const float*)d_in[1];
  const float* maskV = (const float*)d_in[2];
  const float* maskA = (const float*)d_in[3];
  const float* W1w  = (const float*)d_in[4];  const float* W1b  = (const float*)d_in[5];
  const float* W2w  = (const float*)d_in[6];  const float* W2b  = (const float*)d_in[7];
  const float* W3w  = (const float*)d_in[8];  const float* W3b  = (const float*)d_in[9];
  const float* W11w = (const float*)d_in[10]; const float* W11b = (const float*)d_in[11];
  const float* W12w = (const float*)d_in[12]; const float* W12b = (const float*)d_in[13];
  const float* W13w = (const float*)d_in[14]; const float* W13b = (const float*)d_in[15];
  const float* Winw = (const float*)d_in[16]; const float* Winb = (const float*)d_in[17];
  const float* Woutw= (const float*)d_in[18]; const float* Woutb= (const float*)d_in[19];
  const float* ln1g = (const float*)d_in[20]; const float* ln1b = (const float*)d_in[21];
  const float* ln2g = (const float*)d_in[22]; const float* ln2b = (const float*)d_in[23];
  const float* ln3g = (const float*)d_in[24]; const float* ln3b = (const float*)d_in[25];
  const int*   Eidx = (const int*)d_in[26];

  float* outV = (float*)d_out;
  float* outE = outV + (size_t)NN*HH;

  char* ws = (char*)d_ws;
  short* pk = (short*)ws;
  const short* pkW1a  = pk + 0*16384;
  const short* pkW1c  = pk + 1*16384;
  const short* pkW1bb = pk + 2*16384;
  const short* pkW2   = pk + 3*16384;
  const short* pkW3   = pk + 4*16384;
  const short* pkW11a = pk + 5*16384;
  const short* pkW11c = pk + 6*16384;
  const short* pkW11bb= pk + 7*16384;
  const short* pkW12  = pk + 8*16384;
  const short* pkW13  = pk + 9*16384;
  const short* pkWin  = pk + 163840;
  const short* pkWout = pk + 229376;

  short* U1 = (short*)(ws + 1048576);
  short* Z1 = (short*)(ws + 6291456);
  short* U2 = (short*)(ws + 11534336);
  short* Z2 = (short*)(ws + 16777216);
  float* hVmid = (float*)(ws + 22020096);
  short* hEs = (short*)(ws + 33554432);   // bf16 image of h_E, 163.84 MB

  const bool em = ws_size >= (size_t)33554432 + (size_t)NN*KK*HH*2;

  enc_pack<<<288, 256, 0, stream>>>(W1w, W2w, W3w, W11w, W12w, W13w, Winw, Woutw, pk);
  enc_proj<<<313, 256, 0, stream>>>(h_V, pkW1a, pkW1c, W1b, U1, Z1);
  if (em){
    enc_mlp3<0,1><<<NN/4, 512, 0, stream>>>(h_E, U1, Z1, Eidx, maskA, h_V,
                                            ln1g, ln1b, pkW1bb, pkW2, W2b, pkW3, W3b, hVmid, hEs);
  } else {
    enc_mlp3<0,0><<<NN/4, 512, 0, stream>>>(h_E, U1, Z1, Eidx, maskA, h_V,
                                            ln1g, ln1b, pkW1bb, pkW2, W2b, pkW3, W3b, hVmid, nullptr);
  }
  enc_ffn<<<313, 256, 0, stream>>>(hVmid, pkWin, Winb, pkWout, Woutb,
                                   ln2g, ln2b, maskV, outV);
  enc_proj<<<313, 256, 0, stream>>>(outV, pkW11a, pkW11c, W11b, U2, Z2);
  if (em){
    enc_mlp3<1,1><<<NN/4, 512, 0, stream>>>(h_E, U2, Z2, Eidx, nullptr, nullptr,
                                            ln3g, ln3b, pkW11bb, pkW12, W12b, pkW13, W13b, outE, hEs);
  } else {
    enc_mlp3<1,0><<<NN/4, 512, 0, stream>>>(h_E, U2, Z2, Eidx, nullptr, nullptr,
                                            ln3g, ln3b, pkW11bb, pkW12, W12b, pkW13, W13b, outE, nullptr);
  }
}